// Round 17
// baseline (214.045 us; speedup 1.0000x reference)
//
#include <hip/hip_runtime.h>

#define N_NODES 100000
#define N_EDGES 600000
#define DIM 128

typedef __attribute__((ext_vector_type(8))) short bf16x8;
typedef __attribute__((ext_vector_type(4))) float f32x4;

typedef __attribute__((address_space(1))) const unsigned int g_u32;
typedef __attribute__((address_space(3))) unsigned int l_u32;
__device__ __forceinline__ void stage16(const void* g, void* l) {
  __builtin_amdgcn_global_load_lds((g_u32*)g, (l_u32*)l, 16, 0, 0);
}

__device__ __forceinline__ unsigned short f32_to_bf16_rn(float f) {
  unsigned int u = __builtin_bit_cast(unsigned int, f);
  unsigned int r = (u + 0x7FFFu + ((u >> 16) & 1u)) >> 16;
  return (unsigned short)r;
}

// ---------------- prep: zero deg + pack weights (hi) + x -> bf16 hi ------
__global__ __launch_bounds__(256) void prep_k(
    const float* __restrict__ Wl0, const float* __restrict__ Wr0,
    const float* __restrict__ Wl1, const float* __restrict__ Wr1,
    unsigned short* __restrict__ P0, unsigned short* __restrict__ P1,
    const float* __restrict__ x, unsigned short* __restrict__ xhi,
    int* __restrict__ deg) {
  const int gid = blockIdx.x * 256 + threadIdx.x;
  if (gid < N_NODES) deg[gid] = 0;
  if (gid < 65536) {
    const int layer = gid >> 15;
    const int idx = gid & 32767;
    const int j = idx & 7;
    const int l = (idx >> 3) & 63;
    const int nt = (idx >> 9) & 7;
    const int g = idx >> 12;  // 0..7
    const int k = ((g & 3) << 5) + ((l >> 4) << 3) + j;
    const int n = (nt << 4) + (l & 15);
    const float* W = layer ? ((g < 4) ? Wl1 : Wr1) : ((g < 4) ? Wl0 : Wr0);
    (layer ? P1 : P0)[idx] = f32_to_bf16_rn(W[k * 128 + n]);
  } else {
    const int i = gid - 65536;  // one float4 per thread
    if (i < N_NODES * DIM / 4) {
      const float4 v = reinterpret_cast<const float4*>(x)[i];
      const float f[4] = {v.x, v.y, v.z, v.w};
      unsigned short h[4];
#pragma unroll
      for (int j = 0; j < 4; ++j) h[j] = f32_to_bf16_rn(f[j]);
      uint2 hp;
      hp.x = (unsigned)h[0] | ((unsigned)h[1] << 16);
      hp.y = (unsigned)h[2] | ((unsigned)h[3] << 16);
      reinterpret_cast<uint2*>(xhi)[i] = hp;
    }
  }
}

// ---------------- CSR build ----------------
__global__ void hist_k(const int* __restrict__ dst, int* __restrict__ deg) {
  int e = blockIdx.x * blockDim.x + threadIdx.x;
  if (e < N_EDGES) atomicAdd(&deg[dst[e]], 1);
}

__global__ __launch_bounds__(1024) void scan1_k(const int* __restrict__ deg,
                                                int* __restrict__ incl,
                                                int* __restrict__ bsum) {
  __shared__ int wsum[16];
  const int t = threadIdx.x, lane = t & 63, w = t >> 6;
  const int gi = blockIdx.x * 1024 + t;
  int v = (gi < N_NODES) ? deg[gi] : 0;
  int s = v;
#pragma unroll
  for (int off = 1; off < 64; off <<= 1) {
    int u = __shfl_up(s, off);
    if (lane >= off) s += u;
  }
  if (lane == 63) wsum[w] = s;
  __syncthreads();
  if (t < 16) {
    int ws = wsum[t];
#pragma unroll
    for (int off = 1; off < 16; off <<= 1) {
      int u = __shfl_up(ws, off);
      if (t >= off) ws += u;
    }
    wsum[t] = ws;
  }
  __syncthreads();
  const int val = s + (w ? wsum[w - 1] : 0);
  if (gi < N_NODES) incl[gi] = val;
  if (t == 1023) bsum[blockIdx.x] = val;
}

// scan3: each block reduces bsum[0..blockIdx) itself (<=98 ints, L2-hot),
// then rowptr = incl - deg + boff.
__global__ __launch_bounds__(1024) void scan3_k(const int* __restrict__ deg,
                                                const int* __restrict__ incl,
                                                const int* __restrict__ bsum,
                                                int* __restrict__ rowptr,
                                                int* __restrict__ head) {
  __shared__ int spart[2];
  __shared__ int boff_s;
  const int t = threadIdx.x;
  if (t < 128) {
    int v = (t < blockIdx.x) ? bsum[t] : 0;
#pragma unroll
    for (int off = 1; off < 64; off <<= 1) v += __shfl_xor(v, off);
    if ((t & 63) == 0) spart[t >> 6] = v;
  }
  __syncthreads();
  if (t == 0) boff_s = spart[0] + spart[1];
  __syncthreads();
  const int gi = blockIdx.x * 1024 + t;
  if (gi < N_NODES) {
    const int e = incl[gi] - deg[gi] + boff_s;
    rowptr[gi] = e;
    head[gi] = e;
  }
  if (gi == 0) rowptr[N_NODES] = N_EDGES;
}

__global__ void fill_k(const int* __restrict__ src, const int* __restrict__ dst,
                       int* __restrict__ head, int* __restrict__ col) {
  int e = blockIdx.x * blockDim.x + threadIdx.x;
  if (e < N_EDGES) {
    int p = atomicAdd(&head[dst[e]], 1);
    col[p] = src[e];
  }
}

// ---------------- mean aggregation: gather bf16 hi-plane ----------------
__global__ __launch_bounds__(256) void agg_k(
    const unsigned short* __restrict__ plane, const int* __restrict__ rowptr,
    const int* __restrict__ col, unsigned short* __restrict__ mhi) {
  const int t = threadIdx.x;
  const int node = blockIdx.x * 16 + (t >> 4);
  const int q = t & 15;  // 16B granule within the 256B row
  const int beg = rowptr[node], end = rowptr[node + 1];
  const uint4* P = reinterpret_cast<const uint4*>(plane);
  float a[8] = {};

  auto accum = [&](uint4 v) {
    const unsigned int u[4] = {v.x, v.y, v.z, v.w};
#pragma unroll
    for (int w = 0; w < 4; ++w) {
      a[2 * w] += __builtin_bit_cast(float, u[w] << 16);
      a[2 * w + 1] += __builtin_bit_cast(float, u[w] & 0xFFFF0000u);
    }
  };

  for (int i = beg; i < end; i += 4) {
    const int i1 = min(i + 1, end - 1);
    const int i2 = min(i + 2, end - 1);
    const int i3 = min(i + 3, end - 1);
    const int c0 = col[i], c1 = col[i1], c2 = col[i2], c3 = col[i3];
    const uint4 v0 = P[(size_t)c0 * 16 + q];
    const uint4 v1 = P[(size_t)c1 * 16 + q];
    const uint4 v2 = P[(size_t)c2 * 16 + q];
    const uint4 v3 = P[(size_t)c3 * 16 + q];
    accum(v0);
    if (i + 1 < end) accum(v1);
    if (i + 2 < end) accum(v2);
    if (i + 3 < end) accum(v3);
  }

  const int d = end - beg;
  const float inv = 1.0f / (float)(d > 1 ? d : 1);
  unsigned int hw[4];
#pragma unroll
  for (int w = 0; w < 4; ++w) {
    const unsigned short h0 = f32_to_bf16_rn(a[2 * w] * inv);
    const unsigned short h1 = f32_to_bf16_rn(a[2 * w + 1] * inv);
    hw[w] = (unsigned)h0 | ((unsigned)h1 << 16);
  }
  uint4 ho = {hw[0], hw[1], hw[2], hw[3]};
  reinterpret_cast<uint4*>(mhi)[(size_t)node * 16 + q] = ho;
}

// ---------------- MFMA GEMM: out = relu(mean@Wl + b + h@Wr) ----------------
// Wave-private tiles (64 rows x 32 cols per wave), ZERO __syncthreads.
// LDS-DMA ordering: counted s_waitcnt vmcnt(6) drains the previous tile's
// stage16 while keeping the 6 newly-issued ops in flight. Rule #18: hipcc's
// scheduler moves ops across inline-asm waitcnt despite "memory" clobber —
// __builtin_amdgcn_sched_barrier(0) immediately BEFORE and AFTER the wait
// pins the issue segment and blocks ds_read hoisting (m214 r282 fix).
template <int OUTF32>
__global__ __launch_bounds__(256, 4) void gemm_k(
    const unsigned short* __restrict__ Mhi, const unsigned short* __restrict__ Hhi,
    const unsigned short* __restrict__ Bp, const float* __restrict__ bias,
    unsigned short* __restrict__ Ohi, float* __restrict__ Of) {
  __shared__ unsigned short Bl[2][4096];  // 2 x 8 KB; wave w uses its quarter
  const int t = threadIdx.x;
  const int lane = t & 63;
  const int wid = t >> 6;
  const int rbase = blockIdx.x * 64;
  const int lm = lane & 15, lk = lane >> 4;
  size_t r[4];
#pragma unroll
  for (int mt = 0; mt < 4; ++mt)
    r[mt] = (size_t)min(rbase + mt * 16 + lm, N_NODES - 1);

  f32x4 acc[4][2] = {};

  auto stageG = [&](int g, int nb) {
#pragma unroll
    for (int s = 0; s < 2; ++s) {
      const int nt = 2 * wid + s;
      stage16(Bp + ((size_t)(g * 8 + nt) * 64 + lane) * 8,
              &Bl[nb][(nt * 64 + lane) * 8]);
    }
  };
  auto loadA = [&](int g, bf16x8* a) {
    const unsigned short* P = (g < 4) ? Mhi : Hhi;
    const int ke = ((g & 3) << 5) + (lk << 3);
#pragma unroll
    for (int mt = 0; mt < 4; ++mt)
      a[mt] = *reinterpret_cast<const bf16x8*>(P + r[mt] * DIM + ke);
  };

  bf16x8 ca[4], na[4];
  stageG(0, 0);
  loadA(0, ca);

#pragma unroll
  for (int g = 0; g < 8; ++g) {
    const int buf = g & 1;
    if (g < 7) {
      stageG(g + 1, buf ^ 1);  // 2 vmem
      loadA(g + 1, na);        // 4 vmem
      __builtin_amdgcn_sched_barrier(0);  // pin the 6 issues before the wait
      // drain everything older than the 6 just-issued ops: tile g's stage
      // (and its A loads) are complete; next tile stays in flight.
      asm volatile("s_waitcnt vmcnt(6)" ::: "memory");
      __builtin_amdgcn_sched_barrier(0);  // block ds_read hoist (rule #18)
    } else {
      __builtin_amdgcn_sched_barrier(0);
      asm volatile("s_waitcnt vmcnt(0)" ::: "memory");
      __builtin_amdgcn_sched_barrier(0);
    }
#pragma unroll
    for (int s = 0; s < 2; ++s) {
      const int nt = 2 * wid + s;
      const bf16x8 b =
          *reinterpret_cast<const bf16x8*>(&Bl[buf][(nt * 64 + lane) * 8]);
#pragma unroll
      for (int mt = 0; mt < 4; ++mt)
        acc[mt][s] = __builtin_amdgcn_mfma_f32_16x16x32_bf16(ca[mt], b, acc[mt][s], 0, 0, 0);
    }
    if (g < 7) {
#pragma unroll
      for (int mt = 0; mt < 4; ++mt) ca[mt] = na[mt];
    }
  }

#pragma unroll
  for (int s = 0; s < 2; ++s) {
    const int cidx = (2 * wid + s) * 16 + lm;
    const float bv = bias[cidx];
#pragma unroll
    for (int mt = 0; mt < 4; ++mt) {
#pragma unroll
      for (int i = 0; i < 4; ++i) {
        const int rr = rbase + mt * 16 + lk * 4 + i;
        if (rr < N_NODES) {
          float v = acc[mt][s][i] + bv;
          v = fmaxf(v, 0.0f);
          if (OUTF32) {
            Of[(size_t)rr * DIM + cidx] = v;
          } else {
            Ohi[(size_t)rr * DIM + cidx] = f32_to_bf16_rn(v);
          }
        }
      }
    }
  }
}

// ---------------- launcher ----------------
extern "C" void kernel_launch(void* const* d_in, const int* in_sizes, int n_in,
                              void* d_out, int out_size, void* d_ws,
                              size_t ws_size, hipStream_t stream) {
  const float* x = (const float*)d_in[0];
  const int* ei = (const int*)d_in[1];
  const float* Wl0 = (const float*)d_in[2];
  const float* bl0 = (const float*)d_in[3];
  const float* Wr0 = (const float*)d_in[4];
  const float* Wl1 = (const float*)d_in[5];
  const float* bl1 = (const float*)d_in[6];
  const float* Wr1 = (const float*)d_in[7];
  float* out = (float*)d_out;
  const int* src = ei;
  const int* dst = ei + N_EDGES;

  char* p = (char*)d_ws;
  auto alloc = [&](size_t bytes) {
    char* q = p;
    p += (bytes + 255) & ~(size_t)255;
    return q;
  };
  int* deg = (int*)alloc((size_t)N_NODES * 4);
  int* rowptr = (int*)alloc((size_t)(N_NODES + 1) * 4);
  int* head = (int*)alloc((size_t)N_NODES * 4);  // doubles as incl-scan temp
  int* col = (int*)alloc((size_t)N_EDGES * 4);
  int* bsum = (int*)alloc(128 * 4);
  unsigned short* Bp0 = (unsigned short*)alloc(32768 * 2);
  unsigned short* Bp1 = (unsigned short*)alloc(32768 * 2);
  unsigned short* xhi = (unsigned short*)alloc((size_t)N_NODES * DIM * 2);
  unsigned short* mhi = (unsigned short*)alloc((size_t)N_NODES * DIM * 2);
  unsigned short* h1hi = (unsigned short*)alloc((size_t)N_NODES * DIM * 2);

  const int nScanB = (N_NODES + 1023) / 1024;  // 98

  prep_k<<<(65536 + N_NODES * DIM / 4 + 255) / 256, 256, 0, stream>>>(
      Wl0, Wr0, Wl1, Wr1, Bp0, Bp1, x, xhi, deg);
  hist_k<<<(N_EDGES + 255) / 256, 256, 0, stream>>>(dst, deg);
  scan1_k<<<nScanB, 1024, 0, stream>>>(deg, head, bsum);
  scan3_k<<<nScanB, 1024, 0, stream>>>(deg, head, bsum, rowptr, head);
  fill_k<<<(N_EDGES + 255) / 256, 256, 0, stream>>>(src, dst, head, col);

  const int nBlocks = (N_NODES + 63) / 64;    // 1563
  const int aggBlocks = N_NODES / 16;         // 6250

  // layer 0: gather xhi -> mhi; gemm0 (A = mhi, H = xhi) -> h1hi
  agg_k<<<aggBlocks, 256, 0, stream>>>(xhi, rowptr, col, mhi);
  gemm_k<0><<<nBlocks, 256, 0, stream>>>(mhi, xhi, Bp0, bl0, h1hi, nullptr);
  // layer 1: gather h1hi -> mhi; gemm1 (A = mhi, H = h1hi) -> f32 out
  agg_k<<<aggBlocks, 256, 0, stream>>>(h1hi, rowptr, col, mhi);
  gemm_k<1><<<nBlocks, 256, 0, stream>>>(mhi, h1hi, Bp1, bl1, nullptr, out);
}

// Round 18
// 179.273 us; speedup vs baseline: 1.1940x; 1.1940x over previous
//
#include <hip/hip_runtime.h>

#define N_NODES 100000
#define N_EDGES 600000
#define DIM 128

typedef __attribute__((ext_vector_type(8))) short bf16x8;
typedef __attribute__((ext_vector_type(4))) float f32x4;

typedef __attribute__((address_space(1))) const unsigned int g_u32;
typedef __attribute__((address_space(3))) unsigned int l_u32;
__device__ __forceinline__ void stage16(const void* g, void* l) {
  __builtin_amdgcn_global_load_lds((g_u32*)g, (l_u32*)l, 16, 0, 0);
}

__device__ __forceinline__ unsigned short f32_to_bf16_rn(float f) {
  unsigned int u = __builtin_bit_cast(unsigned int, f);
  unsigned int r = (u + 0x7FFFu + ((u >> 16) & 1u)) >> 16;
  return (unsigned short)r;
}
__device__ __forceinline__ float bf16lo(unsigned int u) {
  return __builtin_bit_cast(float, u << 16);
}
__device__ __forceinline__ float bf16hi(unsigned int u) {
  return __builtin_bit_cast(float, u & 0xFFFF0000u);
}

// ---------------- prep: zero deg + pack weights (hi) + x -> bf16 hi ------
__global__ __launch_bounds__(256) void prep_k(
    const float* __restrict__ Wl0, const float* __restrict__ Wr0,
    const float* __restrict__ Wl1, const float* __restrict__ Wr1,
    unsigned short* __restrict__ P0, unsigned short* __restrict__ P1,
    const float* __restrict__ x, unsigned short* __restrict__ xhi,
    int* __restrict__ deg) {
  const int gid = blockIdx.x * 256 + threadIdx.x;
  if (gid < N_NODES) deg[gid] = 0;
  if (gid < 65536) {
    const int layer = gid >> 15;
    const int idx = gid & 32767;
    const int j = idx & 7;
    const int l = (idx >> 3) & 63;
    const int nt = (idx >> 9) & 7;
    const int g = idx >> 12;  // 0..7
    const int k = ((g & 3) << 5) + ((l >> 4) << 3) + j;
    const int n = (nt << 4) + (l & 15);
    const float* W = layer ? ((g < 4) ? Wl1 : Wr1) : ((g < 4) ? Wl0 : Wr0);
    (layer ? P1 : P0)[idx] = f32_to_bf16_rn(W[k * 128 + n]);
  } else {
    const int i = gid - 65536;  // one float4 per thread
    if (i < N_NODES * DIM / 4) {
      const float4 v = reinterpret_cast<const float4*>(x)[i];
      const float f[4] = {v.x, v.y, v.z, v.w};
      unsigned short h[4];
#pragma unroll
      for (int j = 0; j < 4; ++j) h[j] = f32_to_bf16_rn(f[j]);
      uint2 hp;
      hp.x = (unsigned)h[0] | ((unsigned)h[1] << 16);
      hp.y = (unsigned)h[2] | ((unsigned)h[3] << 16);
      reinterpret_cast<uint2*>(xhi)[i] = hp;
    }
  }
}

// ---------------- CSR build ----------------
__global__ void hist_k(const int* __restrict__ dst, int* __restrict__ deg) {
  int e = blockIdx.x * blockDim.x + threadIdx.x;
  if (e < N_EDGES) atomicAdd(&deg[dst[e]], 1);
}

__global__ __launch_bounds__(1024) void scan1_k(const int* __restrict__ deg,
                                                int* __restrict__ incl,
                                                int* __restrict__ bsum) {
  __shared__ int wsum[16];
  const int t = threadIdx.x, lane = t & 63, w = t >> 6;
  const int gi = blockIdx.x * 1024 + t;
  int v = (gi < N_NODES) ? deg[gi] : 0;
  int s = v;
#pragma unroll
  for (int off = 1; off < 64; off <<= 1) {
    int u = __shfl_up(s, off);
    if (lane >= off) s += u;
  }
  if (lane == 63) wsum[w] = s;
  __syncthreads();
  if (t < 16) {
    int ws = wsum[t];
#pragma unroll
    for (int off = 1; off < 16; off <<= 1) {
      int u = __shfl_up(ws, off);
      if (t >= off) ws += u;
    }
    wsum[t] = ws;
  }
  __syncthreads();
  const int val = s + (w ? wsum[w - 1] : 0);
  if (gi < N_NODES) incl[gi] = val;
  if (t == 1023) bsum[blockIdx.x] = val;
}

// scan3: each block reduces bsum[0..blockIdx) itself (<=98 ints, L2-hot).
__global__ __launch_bounds__(1024) void scan3_k(const int* __restrict__ deg,
                                                const int* __restrict__ incl,
                                                const int* __restrict__ bsum,
                                                int* __restrict__ rowptr,
                                                int* __restrict__ head) {
  __shared__ int spart[2];
  __shared__ int boff_s;
  const int t = threadIdx.x;
  if (t < 128) {
    int v = (t < blockIdx.x) ? bsum[t] : 0;
#pragma unroll
    for (int off = 1; off < 64; off <<= 1) v += __shfl_xor(v, off);
    if ((t & 63) == 0) spart[t >> 6] = v;
  }
  __syncthreads();
  if (t == 0) boff_s = spart[0] + spart[1];
  __syncthreads();
  const int gi = blockIdx.x * 1024 + t;
  if (gi < N_NODES) {
    const int e = incl[gi] - deg[gi] + boff_s;
    rowptr[gi] = e;
    head[gi] = e;
  }
  if (gi == 0) rowptr[N_NODES] = N_EDGES;
}

__global__ void fill_k(const int* __restrict__ src, const int* __restrict__ dst,
                       int* __restrict__ head, int* __restrict__ col) {
  int e = blockIdx.x * blockDim.x + threadIdx.x;
  if (e < N_EDGES) {
    int p = atomicAdd(&head[dst[e]], 1);
    col[p] = src[e];
  }
}

// ---------------- mean aggregation: gather bf16 hi-plane -> mhi ---------
__global__ __launch_bounds__(256) void agg_k(
    const unsigned short* __restrict__ plane, const int* __restrict__ rowptr,
    const int* __restrict__ col, unsigned short* __restrict__ mhi) {
  const int t = threadIdx.x;
  const int node = blockIdx.x * 16 + (t >> 4);
  const int q = t & 15;  // 16B granule within the 256B row
  const int beg = rowptr[node], end = rowptr[node + 1];
  const uint4* P = reinterpret_cast<const uint4*>(plane);
  float a[8] = {};

  auto accum = [&](uint4 v) {
    const unsigned int u[4] = {v.x, v.y, v.z, v.w};
#pragma unroll
    for (int w = 0; w < 4; ++w) {
      a[2 * w] += bf16lo(u[w]);
      a[2 * w + 1] += bf16hi(u[w]);
    }
  };

  for (int i = beg; i < end; i += 4) {
    const int i1 = min(i + 1, end - 1);
    const int i2 = min(i + 2, end - 1);
    const int i3 = min(i + 3, end - 1);
    const int c0 = col[i], c1 = col[i1], c2 = col[i2], c3 = col[i3];
    const uint4 v0 = P[(size_t)c0 * 16 + q];
    const uint4 v1 = P[(size_t)c1 * 16 + q];
    const uint4 v2 = P[(size_t)c2 * 16 + q];
    const uint4 v3 = P[(size_t)c3 * 16 + q];
    accum(v0);
    if (i + 1 < end) accum(v1);
    if (i + 2 < end) accum(v2);
    if (i + 3 < end) accum(v3);
  }

  const int d = end - beg;
  const float inv = 1.0f / (float)(d > 1 ? d : 1);
  unsigned int hw[4];
#pragma unroll
  for (int w = 0; w < 4; ++w) {
    const unsigned short h0 = f32_to_bf16_rn(a[2 * w] * inv);
    const unsigned short h1 = f32_to_bf16_rn(a[2 * w + 1] * inv);
    hw[w] = (unsigned)h0 | ((unsigned)h1 << 16);
  }
  uint4 ho = {hw[0], hw[1], hw[2], hw[3]};
  reinterpret_cast<uint4*>(mhi)[(size_t)node * 16 + q] = ho;
}

// ------- fused GEMM: h1 = relu(mean@Wl0+b0+x@Wr0) (in LDS only), then -----
// P1 = h1@Wl1, Q1 = h1@Wr1 + b1. mean(h1)@Wl1 == mean(P1) by linearity, so
// layer 1 needs only a gather of P1 + add Q1 (agg1f_k) — gemm1 eliminated,
// h1 never hits HBM. Pass 1/2 both use the r11-proven 8-g-tile dbuf loop.
// h1 crosses C-layout -> A-fragment via wave-private XOR-swizzled LDS tile
// (byte ^= (row&7)<<4 — G4 recipe for [*][128]-bf16).
__global__ __launch_bounds__(256, 4) void gemm01_k(
    const unsigned short* __restrict__ Mhi, const unsigned short* __restrict__ Xhi,
    const unsigned short* __restrict__ Bp0, const float* __restrict__ bl0,
    const unsigned short* __restrict__ Bp1, const float* __restrict__ bl1,
    unsigned short* __restrict__ P1, unsigned short* __restrict__ Q1) {
  __shared__ unsigned short Bl[2][4096];   // 16 KB B dbuf
  __shared__ unsigned short H1t[4][2048];  // 16 KB: per-wave 16x128 h1 tile
  const int t = threadIdx.x;
  const int lane = t & 63;
  const int wid = t >> 6;
  const int rbase = blockIdx.x * 64 + wid * 16;
  const int lm = lane & 15, lk = lane >> 4;
  const size_t r0 = (size_t)min(rbase + lm, N_NODES - 1);

  auto stageG = [&](const unsigned short* Bp, int g, int nb) {
#pragma unroll
    for (int c = 0; c < 2; ++c) {
      const int e = (c * 256 + t) * 8;
      stage16(Bp + (size_t)g * 4096 + e, &Bl[nb][e]);
    }
  };

  // ---- pass 1: layer-0 GEMM -> h1 in registers ----
  f32x4 acc[8] = {};
  auto loadA = [&](int g) {
    const unsigned short* P = (g < 4) ? Mhi : Xhi;
    const int ke = ((g & 3) << 5) + (lk << 3);
    return *reinterpret_cast<const bf16x8*>(P + r0 * DIM + ke);
  };
  stageG(Bp0, 0, 0);
  bf16x8 ca = loadA(0), na;
  __syncthreads();
#pragma unroll
  for (int g = 0; g < 8; ++g) {
    const int buf = g & 1;
    if (g < 7) {
      stageG(Bp0, g + 1, buf ^ 1);
      na = loadA(g + 1);
    }
#pragma unroll
    for (int nt = 0; nt < 8; ++nt) {
      const bf16x8 b =
          *reinterpret_cast<const bf16x8*>(&Bl[buf][(nt * 64 + lane) * 8]);
      acc[nt] = __builtin_amdgcn_mfma_f32_16x16x32_bf16(ca, b, acc[nt], 0, 0, 0);
    }
    __syncthreads();
    ca = na;
  }

  // epilogue 1: h1 = relu(acc + b0) -> wave-private swizzled LDS tile
  unsigned short* ht = H1t[wid];
#pragma unroll
  for (int nt = 0; nt < 8; ++nt) {
    const int c2 = nt * 16 + lm;
    const float bv = bl0[c2];
#pragma unroll
    for (int i = 0; i < 4; ++i) {
      const int row = lk * 4 + i;
      const float v = fmaxf(acc[nt][i] + bv, 0.0f);
      const int byte = (row << 8) + (c2 << 1);
      const int sw = byte ^ ((row & 7) << 4);
      *reinterpret_cast<unsigned short*>(reinterpret_cast<char*>(ht) + sw) =
          f32_to_bf16_rn(v);
    }
  }

  // ---- pass 2: P1 = h1@Wl1 (g 0-3), Q1 = h1@Wr1 (g 4-7) ----
  f32x4 accP[8] = {}, accQ[8] = {};
  auto loadH = [&](int g) {
    const int byte = (lm << 8) + ((((g & 3) << 5) + (lk << 3)) << 1);
    const int sw = byte ^ ((lm & 7) << 4);
    return *reinterpret_cast<const bf16x8*>(
        reinterpret_cast<const char*>(ht) + sw);
  };
  stageG(Bp1, 0, 0);
  bf16x8 ha = loadH(0), hn;
  __syncthreads();
#pragma unroll
  for (int g = 0; g < 8; ++g) {
    const int buf = g & 1;
    if (g < 7) {
      stageG(Bp1, g + 1, buf ^ 1);
      hn = loadH(g + 1);
    }
#pragma unroll
    for (int nt = 0; nt < 8; ++nt) {
      const bf16x8 b =
          *reinterpret_cast<const bf16x8*>(&Bl[buf][(nt * 64 + lane) * 8]);
      if (g < 4) {
        accP[nt] = __builtin_amdgcn_mfma_f32_16x16x32_bf16(ha, b, accP[nt], 0, 0, 0);
      } else {
        accQ[nt] = __builtin_amdgcn_mfma_f32_16x16x32_bf16(ha, b, accQ[nt], 0, 0, 0);
      }
    }
    __syncthreads();
    ha = hn;
  }

  // epilogue 2: store P1 (no bias/relu), Q1 + b1 (no relu)
#pragma unroll
  for (int nt = 0; nt < 8; ++nt) {
    const int cidx = nt * 16 + lm;
    const float bq = bl1[cidx];
#pragma unroll
    for (int i = 0; i < 4; ++i) {
      const int r = rbase + lk * 4 + i;
      if (r < N_NODES) {
        P1[(size_t)r * DIM + cidx] = f32_to_bf16_rn(accP[nt][i]);
        Q1[(size_t)r * DIM + cidx] = f32_to_bf16_rn(accQ[nt][i] + bq);
      }
    }
  }
}

// ---- final: out = relu(mean_gather(P1) + Q1), f32 ----
__global__ __launch_bounds__(256) void agg1f_k(
    const unsigned short* __restrict__ P1, const unsigned short* __restrict__ Q1,
    const int* __restrict__ rowptr, const int* __restrict__ col,
    float* __restrict__ out) {
  const int t = threadIdx.x;
  const int node = blockIdx.x * 16 + (t >> 4);
  const int q = t & 15;
  const int beg = rowptr[node], end = rowptr[node + 1];
  const uint4* P = reinterpret_cast<const uint4*>(P1);
  float a[8] = {};

  auto accum = [&](uint4 v) {
    const unsigned int u[4] = {v.x, v.y, v.z, v.w};
#pragma unroll
    for (int w = 0; w < 4; ++w) {
      a[2 * w] += bf16lo(u[w]);
      a[2 * w + 1] += bf16hi(u[w]);
    }
  };

  for (int i = beg; i < end; i += 4) {
    const int i1 = min(i + 1, end - 1);
    const int i2 = min(i + 2, end - 1);
    const int i3 = min(i + 3, end - 1);
    const int c0 = col[i], c1 = col[i1], c2 = col[i2], c3 = col[i3];
    const uint4 v0 = P[(size_t)c0 * 16 + q];
    const uint4 v1 = P[(size_t)c1 * 16 + q];
    const uint4 v2 = P[(size_t)c2 * 16 + q];
    const uint4 v3 = P[(size_t)c3 * 16 + q];
    accum(v0);
    if (i + 1 < end) accum(v1);
    if (i + 2 < end) accum(v2);
    if (i + 3 < end) accum(v3);
  }

  const int d = end - beg;
  const float inv = 1.0f / (float)(d > 1 ? d : 1);
  const uint4 qv = reinterpret_cast<const uint4*>(Q1)[(size_t)node * 16 + q];
  const unsigned int qu[4] = {qv.x, qv.y, qv.z, qv.w};
  float o[8];
#pragma unroll
  for (int w = 0; w < 4; ++w) {
    o[2 * w] = fmaxf(a[2 * w] * inv + bf16lo(qu[w]), 0.0f);
    o[2 * w + 1] = fmaxf(a[2 * w + 1] * inv + bf16hi(qu[w]), 0.0f);
  }
  float4 o0 = {o[0], o[1], o[2], o[3]};
  float4 o1 = {o[4], o[5], o[6], o[7]};
  float4* op = reinterpret_cast<float4*>(out + (size_t)node * DIM + q * 8);
  op[0] = o0;
  op[1] = o1;
}

// ---------------- launcher ----------------
extern "C" void kernel_launch(void* const* d_in, const int* in_sizes, int n_in,
                              void* d_out, int out_size, void* d_ws,
                              size_t ws_size, hipStream_t stream) {
  const float* x = (const float*)d_in[0];
  const int* ei = (const int*)d_in[1];
  const float* Wl0 = (const float*)d_in[2];
  const float* bl0 = (const float*)d_in[3];
  const float* Wr0 = (const float*)d_in[4];
  const float* Wl1 = (const float*)d_in[5];
  const float* bl1 = (const float*)d_in[6];
  const float* Wr1 = (const float*)d_in[7];
  float* out = (float*)d_out;
  const int* src = ei;
  const int* dst = ei + N_EDGES;

  char* p = (char*)d_ws;
  auto alloc = [&](size_t bytes) {
    char* q = p;
    p += (bytes + 255) & ~(size_t)255;
    return q;
  };
  int* deg = (int*)alloc((size_t)N_NODES * 4);
  int* rowptr = (int*)alloc((size_t)(N_NODES + 1) * 4);
  int* head = (int*)alloc((size_t)N_NODES * 4);  // doubles as incl-scan temp
  int* col = (int*)alloc((size_t)N_EDGES * 4);
  int* bsum = (int*)alloc(128 * 4);
  unsigned short* Bp0 = (unsigned short*)alloc(32768 * 2);
  unsigned short* Bp1 = (unsigned short*)alloc(32768 * 2);
  unsigned short* xhi = (unsigned short*)alloc((size_t)N_NODES * DIM * 2);
  unsigned short* mhi = (unsigned short*)alloc((size_t)N_NODES * DIM * 2);
  unsigned short* P1hi = (unsigned short*)alloc((size_t)N_NODES * DIM * 2);
  unsigned short* Q1hi = (unsigned short*)alloc((size_t)N_NODES * DIM * 2);

  const int nScanB = (N_NODES + 1023) / 1024;  // 98

  prep_k<<<(65536 + N_NODES * DIM / 4 + 255) / 256, 256, 0, stream>>>(
      Wl0, Wr0, Wl1, Wr1, Bp0, Bp1, x, xhi, deg);
  hist_k<<<(N_EDGES + 255) / 256, 256, 0, stream>>>(dst, deg);
  scan1_k<<<nScanB, 1024, 0, stream>>>(deg, head, bsum);
  scan3_k<<<nScanB, 1024, 0, stream>>>(deg, head, bsum, rowptr, head);
  fill_k<<<(N_EDGES + 255) / 256, 256, 0, stream>>>(src, dst, head, col);

  const int nBlocks = (N_NODES + 63) / 64;  // 1563
  const int aggBlocks = N_NODES / 16;       // 6250

  // layer 0 gather; fused gemm (h1 stays on-chip) -> P1, Q1; final gather
  agg_k<<<aggBlocks, 256, 0, stream>>>(xhi, rowptr, col, mhi);
  gemm01_k<<<nBlocks, 256, 0, stream>>>(mhi, xhi, Bp0, bl0, Bp1, bl1, P1hi,
                                        Q1hi);
  agg1f_k<<<aggBlocks, 256, 0, stream>>>(P1hi, Q1hi, rowptr, col, out);
}

// Round 19
// 177.346 us; speedup vs baseline: 1.2069x; 1.0109x over previous
//
#include <hip/hip_runtime.h>

#define N_NODES 100000
#define N_EDGES 600000
#define DIM 128

typedef __attribute__((ext_vector_type(8))) short bf16x8;
typedef __attribute__((ext_vector_type(4))) float f32x4;

typedef __attribute__((address_space(1))) const unsigned int g_u32;
typedef __attribute__((address_space(3))) unsigned int l_u32;
__device__ __forceinline__ void stage16(const void* g, void* l) {
  __builtin_amdgcn_global_load_lds((g_u32*)g, (l_u32*)l, 16, 0, 0);
}

__device__ __forceinline__ unsigned short f32_to_bf16_rn(float f) {
  unsigned int u = __builtin_bit_cast(unsigned int, f);
  unsigned int r = (u + 0x7FFFu + ((u >> 16) & 1u)) >> 16;
  return (unsigned short)r;
}
__device__ __forceinline__ float bf16lo(unsigned int u) {
  return __builtin_bit_cast(float, u << 16);
}
__device__ __forceinline__ float bf16hi(unsigned int u) {
  return __builtin_bit_cast(float, u & 0xFFFF0000u);
}

// ---------------- prep: zero deg + pack weights (hi) + x -> bf16 hi ------
__global__ __launch_bounds__(256) void prep_k(
    const float* __restrict__ Wl0, const float* __restrict__ Wr0,
    const float* __restrict__ Wl1, const float* __restrict__ Wr1,
    unsigned short* __restrict__ P0, unsigned short* __restrict__ P1,
    const float* __restrict__ x, unsigned short* __restrict__ xhi,
    int* __restrict__ deg) {
  const int gid = blockIdx.x * 256 + threadIdx.x;
  if (gid < N_NODES) deg[gid] = 0;
  if (gid < 65536) {
    const int layer = gid >> 15;
    const int idx = gid & 32767;
    const int j = idx & 7;
    const int l = (idx >> 3) & 63;
    const int nt = (idx >> 9) & 7;
    const int g = idx >> 12;  // 0..7
    const int k = ((g & 3) << 5) + ((l >> 4) << 3) + j;
    const int n = (nt << 4) + (l & 15);
    const float* W = layer ? ((g < 4) ? Wl1 : Wr1) : ((g < 4) ? Wl0 : Wr0);
    (layer ? P1 : P0)[idx] = f32_to_bf16_rn(W[k * 128 + n]);
  } else {
    const int i = gid - 65536;  // one float4 per thread
    if (i < N_NODES * DIM / 4) {
      const float4 v = reinterpret_cast<const float4*>(x)[i];
      const float f[4] = {v.x, v.y, v.z, v.w};
      unsigned short h[4];
#pragma unroll
      for (int j = 0; j < 4; ++j) h[j] = f32_to_bf16_rn(f[j]);
      uint2 hp;
      hp.x = (unsigned)h[0] | ((unsigned)h[1] << 16);
      hp.y = (unsigned)h[2] | ((unsigned)h[3] << 16);
      reinterpret_cast<uint2*>(xhi)[i] = hp;
    }
  }
}

// ---------------- CSR build ----------------
__global__ void hist_k(const int* __restrict__ dst, int* __restrict__ deg) {
  int e = blockIdx.x * blockDim.x + threadIdx.x;
  if (e < N_EDGES) atomicAdd(&deg[dst[e]], 1);
}

__global__ __launch_bounds__(1024) void scan1_k(const int* __restrict__ deg,
                                                int* __restrict__ incl,
                                                int* __restrict__ bsum) {
  __shared__ int wsum[16];
  const int t = threadIdx.x, lane = t & 63, w = t >> 6;
  const int gi = blockIdx.x * 1024 + t;
  int v = (gi < N_NODES) ? deg[gi] : 0;
  int s = v;
#pragma unroll
  for (int off = 1; off < 64; off <<= 1) {
    int u = __shfl_up(s, off);
    if (lane >= off) s += u;
  }
  if (lane == 63) wsum[w] = s;
  __syncthreads();
  if (t < 16) {
    int ws = wsum[t];
#pragma unroll
    for (int off = 1; off < 16; off <<= 1) {
      int u = __shfl_up(ws, off);
      if (t >= off) ws += u;
    }
    wsum[t] = ws;
  }
  __syncthreads();
  const int val = s + (w ? wsum[w - 1] : 0);
  if (gi < N_NODES) incl[gi] = val;
  if (t == 1023) bsum[blockIdx.x] = val;
}

// scan3: each block reduces bsum[0..blockIdx) itself (<=98 ints, L2-hot).
__global__ __launch_bounds__(1024) void scan3_k(const int* __restrict__ deg,
                                                const int* __restrict__ incl,
                                                const int* __restrict__ bsum,
                                                int* __restrict__ rowptr,
                                                int* __restrict__ head) {
  __shared__ int spart[2];
  __shared__ int boff_s;
  const int t = threadIdx.x;
  if (t < 128) {
    int v = (t < blockIdx.x) ? bsum[t] : 0;
#pragma unroll
    for (int off = 1; off < 64; off <<= 1) v += __shfl_xor(v, off);
    if ((t & 63) == 0) spart[t >> 6] = v;
  }
  __syncthreads();
  if (t == 0) boff_s = spart[0] + spart[1];
  __syncthreads();
  const int gi = blockIdx.x * 1024 + t;
  if (gi < N_NODES) {
    const int e = incl[gi] - deg[gi] + boff_s;
    rowptr[gi] = e;
    head[gi] = e;
  }
  if (gi == 0) rowptr[N_NODES] = N_EDGES;
}

__global__ void fill_k(const int* __restrict__ src, const int* __restrict__ dst,
                       int* __restrict__ head, int* __restrict__ col) {
  int e = blockIdx.x * blockDim.x + threadIdx.x;
  if (e < N_EDGES) {
    int p = atomicAdd(&head[dst[e]], 1);
    col[p] = src[e];
  }
}

// ---------------- mean aggregation: gather bf16 hi-plane ----------------
__global__ __launch_bounds__(256) void agg_k(
    const unsigned short* __restrict__ plane, const int* __restrict__ rowptr,
    const int* __restrict__ col, unsigned short* __restrict__ mhi) {
  const int t = threadIdx.x;
  const int node = blockIdx.x * 16 + (t >> 4);
  const int q = t & 15;  // 16B granule within the 256B row
  const int beg = rowptr[node], end = rowptr[node + 1];
  const uint4* P = reinterpret_cast<const uint4*>(plane);
  float a[8] = {};

  auto accum = [&](uint4 v) {
    const unsigned int u[4] = {v.x, v.y, v.z, v.w};
#pragma unroll
    for (int w = 0; w < 4; ++w) {
      a[2 * w] += bf16lo(u[w]);
      a[2 * w + 1] += bf16hi(u[w]);
    }
  };

  for (int i = beg; i < end; i += 4) {
    const int i1 = min(i + 1, end - 1);
    const int i2 = min(i + 2, end - 1);
    const int i3 = min(i + 3, end - 1);
    const int c0 = col[i], c1 = col[i1], c2 = col[i2], c3 = col[i3];
    const uint4 v0 = P[(size_t)c0 * 16 + q];
    const uint4 v1 = P[(size_t)c1 * 16 + q];
    const uint4 v2 = P[(size_t)c2 * 16 + q];
    const uint4 v3 = P[(size_t)c3 * 16 + q];
    accum(v0);
    if (i + 1 < end) accum(v1);
    if (i + 2 < end) accum(v2);
    if (i + 3 < end) accum(v3);
  }

  const int d = end - beg;
  const float inv = 1.0f / (float)(d > 1 ? d : 1);
  unsigned int hw[4];
#pragma unroll
  for (int w = 0; w < 4; ++w) {
    const unsigned short h0 = f32_to_bf16_rn(a[2 * w] * inv);
    const unsigned short h1 = f32_to_bf16_rn(a[2 * w + 1] * inv);
    hw[w] = (unsigned)h0 | ((unsigned)h1 << 16);
  }
  uint4 ho = {hw[0], hw[1], hw[2], hw[3]};
  reinterpret_cast<uint4*>(mhi)[(size_t)node * 16 + q] = ho;
}

// ---------------- MFMA GEMM: out = relu(mean@Wl + b + h@Wr) ----------------
// r11-proven structure: 1563 blocks x 64 rows, 4 waves, wave = 16 rows x
// N=128, 8 g-tile dbuf via global_load_lds, one barrier per g-tile.
// NEW (OUTF32=0): LDS-coalesced bf16 C-store — after the K-loop the B-LDS is
// dead; each wave re-stages its 16x128 bf16 tile there (4 KB/wave = 16 KB),
// then the block copies 64 contiguous 256 B rows out (removes the ~2x write
// amplification of per-lane 2 B scattered stores).
template <int OUTF32>
__global__ __launch_bounds__(256, 4) void gemm_k(
    const unsigned short* __restrict__ Mhi, const unsigned short* __restrict__ Hhi,
    const unsigned short* __restrict__ Bp, const float* __restrict__ bias,
    unsigned short* __restrict__ Ohi, float* __restrict__ Of) {
  __shared__ unsigned short Bl[2][4096];  // 16 KB: B dbuf, then C-tile
  const int t = threadIdx.x;
  const int lane = t & 63;
  const int wid = t >> 6;
  const int rbase = blockIdx.x * 64 + wid * 16;
  const int lm = lane & 15, lk = lane >> 4;
  const size_t r0 = (size_t)min(rbase + lm, N_NODES - 1);

  f32x4 acc[8] = {};

  auto stageG = [&](int g, int nb) {
#pragma unroll
    for (int c = 0; c < 2; ++c) {
      const int e = (c * 256 + t) * 8;  // short index
      stage16(Bp + (size_t)g * 4096 + e, &Bl[nb][e]);
    }
  };
  auto loadA = [&](int g) {
    const unsigned short* P = (g < 4) ? Mhi : Hhi;
    const int ke = ((g & 3) << 5) + (lk << 3);
    return *reinterpret_cast<const bf16x8*>(P + r0 * DIM + ke);
  };

  stageG(0, 0);
  bf16x8 ca = loadA(0), na;
  __syncthreads();

#pragma unroll
  for (int g = 0; g < 8; ++g) {
    const int buf = g & 1;
    if (g < 7) {
      stageG(g + 1, buf ^ 1);
      na = loadA(g + 1);
    }
#pragma unroll
    for (int nt = 0; nt < 8; ++nt) {
      const bf16x8 b =
          *reinterpret_cast<const bf16x8*>(&Bl[buf][(nt * 64 + lane) * 8]);
      acc[nt] = __builtin_amdgcn_mfma_f32_16x16x32_bf16(ca, b, acc[nt], 0, 0, 0);
    }
    __syncthreads();
    ca = na;
  }

  if (OUTF32) {
    // f32 out: quarter-wave stores are already full 64 B lines
#pragma unroll
    for (int nt = 0; nt < 8; ++nt) {
      const int cidx = nt * 16 + lm;
      const float bv = bias[cidx];
#pragma unroll
      for (int i = 0; i < 4; ++i) {
        const int r = rbase + lk * 4 + i;
        if (r < N_NODES)
          Of[(size_t)r * DIM + cidx] = fmaxf(acc[nt][i] + bv, 0.0f);
      }
    }
  } else {
    // bf16 out via LDS: scatter into wave tile, then coalesced row copy
    unsigned short* flat = &Bl[0][0];           // 16 KB, B-LDS now dead
    unsigned short* wt = flat + wid * 2048;     // 4 KB per wave (16x128)
#pragma unroll
    for (int nt = 0; nt < 8; ++nt) {
      const int cidx = nt * 16 + lm;
      const float bv = bias[cidx];
#pragma unroll
      for (int i = 0; i < 4; ++i) {
        const int row = lk * 4 + i;
        wt[row * 128 + cidx] = f32_to_bf16_rn(fmaxf(acc[nt][i] + bv, 0.0f));
      }
    }
    __syncthreads();
    const int row = t >> 2;   // 0..63 (block-local)
    const int seg = t & 3;    // 64 B segment within the 256 B row
    const int gr = blockIdx.x * 64 + row;
    if (gr < N_NODES) {
      const uint4* sp =
          reinterpret_cast<const uint4*>(flat + row * 128 + seg * 32);
      uint4* dp = reinterpret_cast<uint4*>(Ohi + (size_t)gr * DIM + seg * 32);
#pragma unroll
      for (int k = 0; k < 4; ++k) dp[k] = sp[k];
    }
  }
}

// ---------------- launcher ----------------
extern "C" void kernel_launch(void* const* d_in, const int* in_sizes, int n_in,
                              void* d_out, int out_size, void* d_ws,
                              size_t ws_size, hipStream_t stream) {
  const float* x = (const float*)d_in[0];
  const int* ei = (const int*)d_in[1];
  const float* Wl0 = (const float*)d_in[2];
  const float* bl0 = (const float*)d_in[3];
  const float* Wr0 = (const float*)d_in[4];
  const float* Wl1 = (const float*)d_in[5];
  const float* bl1 = (const float*)d_in[6];
  const float* Wr1 = (const float*)d_in[7];
  float* out = (float*)d_out;
  const int* src = ei;
  const int* dst = ei + N_EDGES;

  char* p = (char*)d_ws;
  auto alloc = [&](size_t bytes) {
    char* q = p;
    p += (bytes + 255) & ~(size_t)255;
    return q;
  };
  int* deg = (int*)alloc((size_t)N_NODES * 4);
  int* rowptr = (int*)alloc((size_t)(N_NODES + 1) * 4);
  int* head = (int*)alloc((size_t)N_NODES * 4);  // doubles as incl-scan temp
  int* col = (int*)alloc((size_t)N_EDGES * 4);
  int* bsum = (int*)alloc(128 * 4);
  unsigned short* Bp0 = (unsigned short*)alloc(32768 * 2);
  unsigned short* Bp1 = (unsigned short*)alloc(32768 * 2);
  unsigned short* xhi = (unsigned short*)alloc((size_t)N_NODES * DIM * 2);
  unsigned short* mhi = (unsigned short*)alloc((size_t)N_NODES * DIM * 2);
  unsigned short* h1hi = (unsigned short*)alloc((size_t)N_NODES * DIM * 2);

  const int nScanB = (N_NODES + 1023) / 1024;  // 98

  prep_k<<<(65536 + N_NODES * DIM / 4 + 255) / 256, 256, 0, stream>>>(
      Wl0, Wr0, Wl1, Wr1, Bp0, Bp1, x, xhi, deg);
  hist_k<<<(N_EDGES + 255) / 256, 256, 0, stream>>>(dst, deg);
  scan1_k<<<nScanB, 1024, 0, stream>>>(deg, head, bsum);
  scan3_k<<<nScanB, 1024, 0, stream>>>(deg, head, bsum, rowptr, head);
  fill_k<<<(N_EDGES + 255) / 256, 256, 0, stream>>>(src, dst, head, col);

  const int nBlocks = (N_NODES + 63) / 64;    // 1563
  const int aggBlocks = N_NODES / 16;         // 6250

  // layer 0: gather xhi -> mhi; gemm0 (A = mhi, H = xhi) -> h1hi
  agg_k<<<aggBlocks, 256, 0, stream>>>(xhi, rowptr, col, mhi);
  gemm_k<0><<<nBlocks, 256, 0, stream>>>(mhi, xhi, Bp0, bl0, h1hi, nullptr);
  // layer 1: gather h1hi -> mhi; gemm1 (A = mhi, H = h1hi) -> f32 out
  agg_k<<<aggBlocks, 256, 0, stream>>>(h1hi, rowptr, col, mhi);
  gemm_k<1><<<nBlocks, 256, 0, stream>>>(mhi, h1hi, Bp1, bl1, nullptr, out);
}